// Round 9
// baseline (114604.602 us; speedup 1.0000x reference)
//
#include <hip/hip_runtime.h>
#include <hip/hip_bf16.h>

// Problem: B=16,S=64 -> BS=1024 sequences, L=128 tokens, D=512, F=256 filters
// per conv width Kw in {3,4,5}, V=30000.
// out[bs, c*256 + f] = relu(max_t (conv_c(x)[t,f]) + b_c[f]), fp32.
//
// R5: slab, 8 waves (2/SIMD): 399 us — latency unhidden, pipeline collapsed.
// R8: 16 waves (4/SIMD, 128-reg cap): pipeline HELD but SPILLED (68 GB
//     scratch writes, 58 ms). 64x64 tile + pipeline needs ~130 regs.
// R9: 12 waves (3/SIMD, 170-reg cap) = wm(2) x wn(2) x ks(3 K-split);
//     block tile M128 x N128, grid 6144 = (bs, conv, filter-half). Slab
//     staged once; B fragment-packed global, depth-2 register prefetch;
//     A JIT ds_reads (conflict-free at stride 520). Epilogue: 3-way partial
//     sum via LDS in r*64+lane layout (fixes R8's 9.4e7 bank conflicts).

typedef __bf16 bf16x8 __attribute__((ext_vector_type(8)));
typedef float f32x16 __attribute__((ext_vector_type(16)));

#define XROWS 132                     // 128 real + 4 zero pad (K=5 window)
#define XELEMS ((size_t)1024 * XROWS * 512)
#define SLAB_STRIDE 520               // 512 + 8 bf16 pad (bank spread)
#define SLAB_BYTES (XROWS * SLAB_STRIDE * 2)   // 137280 B
#define WQ_ELEMS 1572864              // 3072 chunks * 512 elem

__device__ __forceinline__ void async16(const void* g, void* l) {
    __builtin_amdgcn_global_load_lds(
        (const __attribute__((address_space(1))) void*)g,
        (__attribute__((address_space(3))) void*)l, 16, 0, 0);
}

// ---------------- pack_x: x[bs][t][d] = bf16(embed[text[bs,t], d]) ----------
__global__ void pack_x_kernel(const int* __restrict__ text,
                              const float* __restrict__ embed,
                              __bf16* __restrict__ x) {
    const int tid  = threadIdx.x;
    const int rr   = blockIdx.x * 4 + (tid >> 6);   // global row 0..135167
    const int lane = tid & 63;
    const int bs   = rr / XROWS;
    const int t    = rr - bs * XROWS;
    __bf16* dst = x + (size_t)rr * 512 + lane * 8;
    bf16x8 o = {};
    if (t < 128) {
        const int token = text[bs * 128 + t];
        const float* src = embed + (size_t)token * 512 + lane * 8;
        const float4 v0 = *(const float4*)(src);
        const float4 v1 = *(const float4*)(src + 4);
        o[0] = (__bf16)v0.x; o[1] = (__bf16)v0.y;
        o[2] = (__bf16)v0.z; o[3] = (__bf16)v0.w;
        o[4] = (__bf16)v1.x; o[5] = (__bf16)v1.y;
        o[6] = (__bf16)v1.z; o[7] = (__bf16)v1.w;
    }
    *(bf16x8*)dst = o;
}

// -------- pack_w: 32x32x16 B-fragment-ordered chunks (R8-verified) ----------
// Chunk g = (c, gk, n32), 1024 B = 64 lanes x 16 B; gk = 16-k group, n32 =
// 32-filter group. Element (lane, j):
//   f = n32*32 + (lane&31), k = gk*16 + (lane>>5)*8 + j, tap = k>>9, d = k&511
//   src = w_c[f][d][tap]   (w layout [F][D][Kw]).
__global__ void pack_w_kernel(const float* __restrict__ w3,
                              const float* __restrict__ w4,
                              const float* __restrict__ w5,
                              __bf16* __restrict__ wq) {
    const int t    = blockIdx.x * 256 + threadIdx.x;  // 0..196607
    const int g    = t >> 6;                          // chunk 0..3071
    const int lane = t & 63;
    int rel, Kw; const float* w;
    if (g < 768)       { rel = g;        Kw = 3; w = w3; }
    else if (g < 1792) { rel = g - 768;  Kw = 4; w = w4; }
    else               { rel = g - 1792; Kw = 5; w = w5; }
    const int gk  = rel >> 3;
    const int n32 = rel & 7;
    const int f   = n32 * 32 + (lane & 31);
    const int k0  = gk * 16 + (lane >> 5) * 8;        // never straddles a tap
    const int tap = k0 >> 9;
    const int d0  = k0 & 511;
    const float* src = w + ((size_t)f * 512 + d0) * Kw + tap;
    bf16x8 o;
#pragma unroll
    for (int j = 0; j < 8; ++j) o[j] = (__bf16)src[j * Kw];
    *(bf16x8*)(wq + (size_t)t * 8) = o;
}

// ---------------- slab-resident conv GEMM + max + bias + relu ---------------
// Grid 6144 = (bs, conv, nh), XCD decode. 768 thr = 12 waves: wm(2) x wn(2)
// x ks(3). Wave tile 64x64 = 2x2 of 32x32x16 bf16; wave does kq = ks mod 3.
// A: persistent LDS slab. B: fragment-packed global, depth-2 prefetch.
// No barriers in the K-loop. Epilogue: 3-way sum via LDS, then max/bias/relu.
__global__ __launch_bounds__(768, 3) void conv_gemm_kernel(
        const __bf16* __restrict__ x,
        const __bf16* __restrict__ wq,
        const float* __restrict__ b3,
        const float* __restrict__ b4,
        const float* __restrict__ b5,
        float* __restrict__ out) {
    extern __shared__ __bf16 slab[];   // XROWS x SLAB_STRIDE bf16

    const int tid  = threadIdx.x;
    const int wave = tid >> 6;
    const int lane = tid & 63;

    const int lin = blockIdx.x;           // 0..6143
    const int xcd = lin & 7;
    const int idx = lin >> 3;             // 0..767
    const int bsh = idx / 6;
    const int rem = idx - bsh * 6;
    const int c   = rem >> 1;             // conv 0..2 (Kw = 3+c)
    const int nh  = rem & 1;              // filter half (128 cols)
    const int bs  = bsh * 8 + xcd;        // 0..1023
    const int nkq = (3 + c) << 4;         // 48 / 64 / 80
    const int cbase = (c == 0) ? 0 : (c == 1) ? 393216 : 917504;  // elems

    const __bf16* xb = x + (size_t)bs * (XROWS * 512);

    // ---- stage slab once ----
    for (int r = wave; r < XROWS; r += 12)
        async16(xb + r * 512 + lane * 8, &slab[r * SLAB_STRIDE]);
    __syncthreads();

    // ---- wave decode: wm(2) x wn(2) x ks(3) ----
    const int wm = wave & 1;
    const int wn = (wave >> 1) & 1;
    const int ks = wave >> 2;             // 0..2 K-split residue
    const int l31 = lane & 31, lh = lane >> 5;

    // A frag (32x32x16): row = wm*64 + mt*32 + l31 + tap, k = lh*8 + j (+16)
    const __bf16* apb = slab + (wm * 64 + l31) * SLAB_STRIDE + lh * 8;
    // B frag: chunk (gk, n32), n32 = nh*4 + wn*2 + {0,1}; gk = 2kq, 2kq+1.
    const __bf16* bp = wq + cbase + (size_t)(nh * 4 + wn * 2) * 512 + lane * 8;

    f32x16 acc[2][2] = {};
    bf16x8 B2[2][4];

    auto loadB = [&](bf16x8* d, int kq) {
        const __bf16* p = bp + (size_t)kq * 8192;
        d[0] = *(const bf16x8*)(p);          // gk even, n32a
        d[1] = *(const bf16x8*)(p + 512);    // gk even, n32b
        d[2] = *(const bf16x8*)(p + 4096);   // gk odd,  n32a
        d[3] = *(const bf16x8*)(p + 4608);   // gk odd,  n32b
    };

    loadB(B2[0], ks);
    loadB(B2[1], ks + 3);

    const int ni = (nkq - ks + 2) / 3;    // per-wave iterations
#pragma unroll 2
    for (int i = 0; i < ni; ++i) {
        const int kq  = ks + 3 * i;       // this wave's 32-k chunk
        const int tap = kq >> 4;
        const __bf16* a0 = apb + tap * SLAB_STRIDE + (kq & 15) * 32;
        const int cur = i & 1;
        bf16x8 al = *(const bf16x8*)(a0);
        bf16x8 ah = *(const bf16x8*)(a0 + 32 * SLAB_STRIDE);
        acc[0][0] = __builtin_amdgcn_mfma_f32_32x32x16_bf16(al, B2[cur][0], acc[0][0], 0, 0, 0);
        acc[0][1] = __builtin_amdgcn_mfma_f32_32x32x16_bf16(al, B2[cur][1], acc[0][1], 0, 0, 0);
        acc[1][0] = __builtin_amdgcn_mfma_f32_32x32x16_bf16(ah, B2[cur][0], acc[1][0], 0, 0, 0);
        acc[1][1] = __builtin_amdgcn_mfma_f32_32x32x16_bf16(ah, B2[cur][1], acc[1][1], 0, 0, 0);
        al = *(const bf16x8*)(a0 + 16);
        ah = *(const bf16x8*)(a0 + 16 + 32 * SLAB_STRIDE);
        acc[0][0] = __builtin_amdgcn_mfma_f32_32x32x16_bf16(al, B2[cur][2], acc[0][0], 0, 0, 0);
        acc[0][1] = __builtin_amdgcn_mfma_f32_32x32x16_bf16(al, B2[cur][3], acc[0][1], 0, 0, 0);
        acc[1][0] = __builtin_amdgcn_mfma_f32_32x32x16_bf16(ah, B2[cur][2], acc[1][0], 0, 0, 0);
        acc[1][1] = __builtin_amdgcn_mfma_f32_32x32x16_bf16(ah, B2[cur][3], acc[1][1], 0, 0, 0);
        int kn = kq + 6;                  // depth-2 prefetch (stride 3)
        kn = (kn < nkq) ? kn : (nkq - 1); // uniform clamp; dummy never used
        loadB(B2[cur], kn);
    }

    // ---- epilogue: ks-partners SUM via LDS, then max/bias/relu ----
    __syncthreads();                      // slab A-data dead from here
    float* sf = (float*)slab;             // 34320 f32 available
    const int p = wm * 2 + wn;            // tile id 0..3

    if (ks > 0) {                         // partials in r*64+lane layout
        float* tb = sf + (ks - 1) * 16384 + p * 4096;
#pragma unroll
        for (int q = 0; q < 4; ++q)
#pragma unroll
            for (int r = 0; r < 16; ++r)
                tb[q * 1024 + r * 64 + lane] = acc[q >> 1][q & 1][r];
    }
    __syncthreads();
    if (ks == 0) {
        const float* t1 = sf + p * 4096;
        const float* t2 = sf + 16384 + p * 4096;
#pragma unroll
        for (int q = 0; q < 4; ++q)
#pragma unroll
            for (int r = 0; r < 16; ++r)
                acc[q >> 1][q & 1][r] += t1[q * 1024 + r * 64 + lane]
                                       + t2[q * 1024 + r * 64 + lane];
        // C 32x32 layout: col = lane&31, row = (r&3) + 8*(r>>2) + 4*lh
        const int Tv = 126 - c;           // valid t count
        float* red2 = sf + 32768;         // [2][128] wm-partials
#pragma unroll
        for (int nt = 0; nt < 2; ++nt) {
            float mx = -3.0e38f;
#pragma unroll
            for (int mt = 0; mt < 2; ++mt) {
                const int rbase = wm * 64 + mt * 32 + 4 * lh;
#pragma unroll
                for (int r = 0; r < 16; ++r) {
                    const int row = rbase + (r & 3) + 8 * (r >> 2);
                    const float v = acc[mt][nt][r];
                    if (row < Tv) mx = fmaxf(mx, v);
                }
            }
            mx = fmaxf(mx, __shfl_xor(mx, 32, 64));
            if (lh == 0)
                red2[wm * 128 + wn * 64 + nt * 32 + l31] = mx;
        }
    }
    __syncthreads();
    if (tid < 128) {
        const float* bias = (c == 0) ? b3 : (c == 1) ? b4 : b5;
        const float* red2 = sf + 32768;
        const int fg = nh * 128 + tid;    // filter within conv
        float v = fmaxf(red2[tid], red2[128 + tid]) + bias[fg];
        out[(size_t)bs * 768 + c * 256 + fg] = fmaxf(v, 0.f);
    }
}

extern "C" void kernel_launch(void* const* d_in, const int* in_sizes, int n_in,
                              void* d_out, int out_size, void* d_ws, size_t ws_size,
                              hipStream_t stream) {
    const int*   text  = (const int*)d_in[0];
    const float* embed = (const float*)d_in[1];
    const float* w3    = (const float*)d_in[2];
    const float* b3    = (const float*)d_in[3];
    const float* w4    = (const float*)d_in[4];
    const float* b4    = (const float*)d_in[5];
    const float* w5    = (const float*)d_in[6];
    const float* b5    = (const float*)d_in[7];
    float* out = (float*)d_out;

    __bf16* x  = (__bf16*)d_ws;                 // 1024*132*512 bf16 = 138.4 MB
    __bf16* wq = x + XELEMS;                    // 1572864 bf16 = 3.1 MB

    (void)hipFuncSetAttribute((const void*)conv_gemm_kernel,
                              hipFuncAttributeMaxDynamicSharedMemorySize,
                              SLAB_BYTES);

    pack_x_kernel<<<1024 * XROWS / 4, 256, 0, stream>>>(text, embed, x);
    pack_w_kernel<<<768, 256, 0, stream>>>(w3, w4, w5, wq);
    conv_gemm_kernel<<<6144, 768, SLAB_BYTES, stream>>>(x, wq, b3, b4, b5, out);
}

// Round 10
// 43680.069 us; speedup vs baseline: 2.6237x; 2.6237x over previous
//
#include <hip/hip_runtime.h>
#include <hip/hip_bf16.h>

// Problem: B=16,S=64 -> BS=1024 sequences, L=128 tokens, D=512, F=256 filters
// per conv width Kw in {3,4,5}, V=30000.
// out[bs, c*256 + f] = relu(max_t (conv_c(x)[t,f]) + b_c[f]), fp32.
//
// R5:  slab, 8 waves, 16x16x32/f32x4: 399 us, VGPR 60 (pipeline collapsed).
// R8/9: 32x32x16/f32x16 variants SPILLED (48-68 GB scratch): compiler
//      targets ~6-8 waves/EU (VGPR 60-84) regardless of launch_bounds MIN,
//      and f32x16 accs blow that budget -> per-iteration scratch traffic.
// R10: K-split geometry rebuilt from proven-codegen parts ONLY:
//      - 16x16x32 MFMA + f32x4 accs (never spilled in R1-R6)
//      - amdgpu_waves_per_eu(3,3): min=max pins the budget at 170 regs,
//        preventing both spill AND the R5 pipeline collapse
//      - 12 waves = wm2 x wn2 x ks3, wave tile 64x64, grid 6144 (bs,c,nh)
//      - R2-proven XOR-swizzle slab (conflict-free A reads, stride 512)
//      Epilogue: ks-partners sum via LDS (float4, 2-way=free), then max.

typedef __bf16 bf16x8 __attribute__((ext_vector_type(8)));
typedef float f32x4 __attribute__((ext_vector_type(4)));

#define XROWS 132                     // 128 real + 4 zero pad (K=5 window)
#define XELEMS ((size_t)1024 * XROWS * 512)
#define SLAB_BYTES (XROWS * 512 * 2)  // 135168 B
#define WQ_ELEMS 1572864              // 3072 chunks * 512 elem

__device__ __forceinline__ void async16(const void* g, void* l) {
    __builtin_amdgcn_global_load_lds(
        (const __attribute__((address_space(1))) void*)g,
        (__attribute__((address_space(3))) void*)l, 16, 0, 0);
}

// ---------------- pack_x: x[bs][t][d] = bf16(embed[text[bs,t], d]) ----------
__global__ void pack_x_kernel(const int* __restrict__ text,
                              const float* __restrict__ embed,
                              __bf16* __restrict__ x) {
    const int tid  = threadIdx.x;
    const int rr   = blockIdx.x * 4 + (tid >> 6);   // global row 0..135167
    const int lane = tid & 63;
    const int bs   = rr / XROWS;
    const int t    = rr - bs * XROWS;
    __bf16* dst = x + (size_t)rr * 512 + lane * 8;
    bf16x8 o = {};
    if (t < 128) {
        const int token = text[bs * 128 + t];
        const float* src = embed + (size_t)token * 512 + lane * 8;
        const float4 v0 = *(const float4*)(src);
        const float4 v1 = *(const float4*)(src + 4);
        o[0] = (__bf16)v0.x; o[1] = (__bf16)v0.y;
        o[2] = (__bf16)v0.z; o[3] = (__bf16)v0.w;
        o[4] = (__bf16)v1.x; o[5] = (__bf16)v1.y;
        o[6] = (__bf16)v1.z; o[7] = (__bf16)v1.w;
    }
    *(bf16x8*)dst = o;
}

// -------- pack_w: 16x16x32 MFMA-fragment-ordered chunks (R5-verified) -------
// Chunk g = (c, kq, n16), 1024 B = 64 lanes x 16 B. Element (lane, j):
//   f = n16*16 + (lane&15), k = kq*32 + (lane>>4)*8 + j, tap = k>>9, d = k&511
//   src = w_c[f][d][tap]  (layout [F][D][Kw]).
__global__ void pack_w_kernel(const float* __restrict__ w3,
                              const float* __restrict__ w4,
                              const float* __restrict__ w5,
                              __bf16* __restrict__ wq) {
    const int t    = blockIdx.x * 256 + threadIdx.x;  // 0..196607
    const int g    = t >> 6;                          // chunk 0..3071
    const int lane = t & 63;
    int rel, Kw; const float* w;
    if (g < 768)       { rel = g;        Kw = 3; w = w3; }
    else if (g < 1792) { rel = g - 768;  Kw = 4; w = w4; }
    else               { rel = g - 1792; Kw = 5; w = w5; }
    const int kq  = rel >> 4;
    const int n16 = rel & 15;
    const int f   = n16 * 16 + (lane & 15);
    const int k0  = kq * 32 + (lane >> 4) * 8;        // never straddles a tap
    const int tap = k0 >> 9;
    const int d0  = k0 & 511;
    const float* src = w + ((size_t)f * 512 + d0) * Kw + tap;
    bf16x8 o;
#pragma unroll
    for (int j = 0; j < 8; ++j) o[j] = (__bf16)src[j * Kw];
    *(bf16x8*)(wq + (size_t)t * 8) = o;
}

// ---------------- slab-resident conv GEMM + max + bias + relu ---------------
// Grid 6144 = (bs, conv, nh), XCD decode. 768 thr = 12 waves: wm(2) x wn(2)
// x ks(3). Wave tile 64x64 = 4x4 of 16x16x32; wave does kq == ks (mod 3).
// Slab XOR swizzle: logical 16B block lb of row r lives at block lb^(r&7).
// B: fragment-packed global chunks, depth-2 register prefetch. No barriers
// in the K-loop.
__global__ __launch_bounds__(768)
__attribute__((amdgpu_waves_per_eu(3, 3)))
void conv_gemm_kernel(
        const __bf16* __restrict__ x,
        const __bf16* __restrict__ wq,
        const float* __restrict__ b3,
        const float* __restrict__ b4,
        const float* __restrict__ b5,
        float* __restrict__ out) {
    extern __shared__ __bf16 slab[];   // XROWS x 512 bf16, XOR-swizzled

    const int tid  = threadIdx.x;
    const int wave = tid >> 6;
    const int lane = tid & 63;

    const int lin = blockIdx.x;           // 0..6143
    const int xcd = lin & 7;
    const int idx = lin >> 3;             // 0..767
    const int bsh = idx / 6;
    const int rem = idx - bsh * 6;
    const int c   = rem >> 1;             // conv 0..2 (Kw = 3+c)
    const int nh  = rem & 1;              // filter half (128 cols)
    const int bs  = bsh * 8 + xcd;        // 0..1023
    const int nkq = (3 + c) << 4;         // 48 / 64 / 80
    const int cbase = (c == 0) ? 0 : (c == 1) ? 393216 : 917504;  // elems

    const __bf16* xb = x + (size_t)bs * (XROWS * 512);

    // ---- stage slab once, XOR-swizzled (lane holds logical blk lane^(r&7))
    for (int r = wave; r < XROWS; r += 12)
        async16(xb + r * 512 + ((lane ^ (r & 7)) << 3), &slab[r * 512]);
    __syncthreads();

    // ---- wave decode: wm(2) x wn(2) x ks(3) ----
    const int wm = wave & 1;
    const int wn = (wave >> 1) & 1;
    const int ks = wave >> 2;             // 0..2 K-split residue
    const int lm = lane & 15, lk = lane >> 4;

    // A frag (16x16x32): row = wm*64 + mt*16 + lm + tap; k = lk*8 + j.
    // Logical 16B block within row = (kq&15)*4 + lk; physical = lb^(row&7),
    // row&7 == (lm + tap) & 7.
    const __bf16* apb = slab + (wm * 64 + lm) * 512;
    // B frag: chunk (kq, n16), n16 = nh*8 + wn*4 + {0..3}.
    const __bf16* bp = wq + cbase + (size_t)(nh * 8 + wn * 4) * 512 + lane * 8;

    f32x4 acc[4][4] = {};
    bf16x8 B2[2][4];

    auto loadB = [&](bf16x8* d, int kq) {
        const __bf16* p = bp + (size_t)kq * 8192;
        d[0] = *(const bf16x8*)(p);
        d[1] = *(const bf16x8*)(p + 512);
        d[2] = *(const bf16x8*)(p + 1024);
        d[3] = *(const bf16x8*)(p + 1536);
    };

    loadB(B2[0], ks);
    loadB(B2[1], ks + 3);                 // ks+3 <= 5 < 48 always valid

    const int ni = (nkq - ks + 2) / 3;    // per-wave iterations
    for (int i = 0; i < ni; ++i) {
        const int kq  = ks + 3 * i;       // this wave's 32-k chunk
        const int tap = kq >> 4;
        const int rx7 = (lm + tap) & 7;   // row&7 for this lane/tap
        const int lb  = ((kq & 15) << 2) | lk;          // logical 16B block
        const __bf16* a0 = apb + tap * 512 + ((lb ^ rx7) << 3);
        const int cur = i & 1;
        bf16x8 a[4];
#pragma unroll
        for (int mt = 0; mt < 4; ++mt)
            a[mt] = *(const bf16x8*)(a0 + mt * (16 * 512));
#pragma unroll
        for (int mt = 0; mt < 4; ++mt)
#pragma unroll
            for (int nt = 0; nt < 4; ++nt)
                acc[mt][nt] = __builtin_amdgcn_mfma_f32_16x16x32_bf16(
                    a[mt], B2[cur][nt], acc[mt][nt], 0, 0, 0);
        int kn = kq + 6;                  // depth-2 prefetch (stride 3)
        kn = (kn < nkq) ? kn : (nkq - 1); // uniform clamp; dummy never used
        loadB(B2[cur], kn);
    }

    // ---- epilogue: ks-partners SUM via LDS, then max/bias/relu ----
    __syncthreads();                      // slab A-data dead from here
    float* sf = (float*)slab;             // 33792 f32 available
    const int p = wave & 3;               // (wm,wn) tile id 0..3

    if (ks > 0) {                         // partials: frag q, lane*4 floats
        float* tb = sf + (ks - 1) * 16384 + p * 4096;
#pragma unroll
        for (int mt = 0; mt < 4; ++mt)
#pragma unroll
            for (int nt = 0; nt < 4; ++nt)
                *(f32x4*)&tb[(mt * 4 + nt) * 256 + lane * 4] = acc[mt][nt];
    }
    __syncthreads();
    if (ks == 0) {
        const float* t1 = sf + p * 4096 + lane * 4;
        const float* t2 = sf + 16384 + p * 4096 + lane * 4;
#pragma unroll
        for (int mt = 0; mt < 4; ++mt)
#pragma unroll
            for (int nt = 0; nt < 4; ++nt) {
                const f32x4 v1 = *(const f32x4*)&t1[(mt * 4 + nt) * 256];
                const f32x4 v2 = *(const f32x4*)&t2[(mt * 4 + nt) * 256];
                acc[mt][nt] += v1 + v2;
            }
    }
    __syncthreads();                      // partials consumed; reuse for red
    float* red2 = sf;                     // [2][128] wm-partials
    if (ks == 0) {
        // C 16x16 layout: col = lane&15, row = lk*4 + r
        const int Tv = 126 - c;           // valid t count
#pragma unroll
        for (int nt = 0; nt < 4; ++nt) {
            float mx = -3.0e38f;
#pragma unroll
            for (int mt = 0; mt < 4; ++mt) {
                const int mb = wm * 64 + mt * 16 + lk * 4;
#pragma unroll
                for (int r = 0; r < 4; ++r) {
                    const float v = acc[mt][nt][r];
                    if (mb + r < Tv) mx = fmaxf(mx, v);
                }
            }
            mx = fmaxf(mx, __shfl_xor(mx, 16, 64));
            mx = fmaxf(mx, __shfl_xor(mx, 32, 64));
            if (lk == 0)
                red2[wm * 128 + wn * 64 + nt * 16 + lm] = mx;
        }
    }
    __syncthreads();
    if (tid < 128) {
        const float* bias = (c == 0) ? b3 : (c == 1) ? b4 : b5;
        const int fg = nh * 128 + tid;    // filter within conv
        float v = fmaxf(red2[tid], red2[128 + tid]) + bias[fg];
        out[(size_t)bs * 768 + c * 256 + fg] = fmaxf(v, 0.f);
    }
}

extern "C" void kernel_launch(void* const* d_in, const int* in_sizes, int n_in,
                              void* d_out, int out_size, void* d_ws, size_t ws_size,
                              hipStream_t stream) {
    const int*   text  = (const int*)d_in[0];
    const float* embed = (const float*)d_in[1];
    const float* w3    = (const float*)d_in[2];
    const float* b3    = (const float*)d_in[3];
    const float* w4    = (const float*)d_in[4];
    const float* b4    = (const float*)d_in[5];
    const float* w5    = (const float*)d_in[6];
    const float* b5    = (const float*)d_in[7];
    float* out = (float*)d_out;

    __bf16* x  = (__bf16*)d_ws;                 // 1024*132*512 bf16 = 138.4 MB
    __bf16* wq = x + XELEMS;                    // 1572864 bf16 = 3.1 MB

    (void)hipFuncSetAttribute((const void*)conv_gemm_kernel,
                              hipFuncAttributeMaxDynamicSharedMemorySize,
                              SLAB_BYTES);

    pack_x_kernel<<<1024 * XROWS / 4, 256, 0, stream>>>(text, embed, x);
    pack_w_kernel<<<768, 256, 0, stream>>>(w3, w4, w5, wq);
    conv_gemm_kernel<<<6144, 768, SLAB_BYTES, stream>>>(x, wq, b3, b4, b5, out);
}